// Round 7
// baseline (2367.512 us; speedup 1.0000x reference)
//
#include <hip/hip_runtime.h>

#define TT 2048
#define NB 256   // 2 batch elements per block

__device__ __forceinline__ float rcpf(float x) { return __builtin_amdgcn_rcpf(x); }
__device__ __forceinline__ float fsig(float x) { return rcpf(1.0f + __expf(-x)); }
__device__ __forceinline__ float ftanh(float x) {
    return fmaf(2.0f, rcpf(1.0f + __expf(-2.0f * x)), -1.0f);
}

// DPP add-from-shifted, old=src bound_ctrl=0: 2 instrs, no zero-init mov.
// Low lanes accumulate garbage; the lane-63 prefix path is exact:
// after shr1/2/4/8 lanes 15/31/47/63 hold their row sums; bcast15 adds
// row2->row3 (lane47->63); bcast31 adds rows01 (lane31)->lane63.
template<int C>
__device__ __forceinline__ float dppmov(float s) {
    return __int_as_float(__builtin_amdgcn_update_dpp(
        __float_as_int(s), __float_as_int(s), C, 0xF, 0xF, false));
}
__device__ __forceinline__ float wave_sum63(float s) {
    s += dppmov<0x111>(s);   // row_shr:1
    s += dppmov<0x112>(s);   // row_shr:2
    s += dppmov<0x114>(s);   // row_shr:4
    s += dppmov<0x118>(s);   // row_shr:8
    s += dppmov<0x142>(s);   // row_bcast:15
    s += dppmov<0x143>(s);   // row_bcast:31
    return s;                // lane 63 = wave total
}
// Quad broadcast: all lanes valid -> single v_mov_b32_dpp.
template<int Q>
__device__ __forceinline__ float qbcast(float x) {
    return __int_as_float(__builtin_amdgcn_update_dpp(
        __float_as_int(x), __float_as_int(x), Q * 0x55, 0xF, 0xF, false));
}

// Block = 4 waves = 256 threads, handles TWO batch elements (streams A,B)
// sharing the 65 register-resident W1 weights per lane (weights are batch-
// independent). Quad-gate layout (R6): lane = 4*u'+g, unit = wave*16+u'.
// Interleaved A/B phase-A gives ~8 independent FMA chains so ONE wave/SIMD
// sustains full issue. Unroll x2 => compile-time LDS parity. One barrier per
// step covers both streams. Layer-2 scalar chains for A,B run on wave2
// lanes 0/32 in a single exec pass (2-step lag, zp ring). h2 staged in LDS,
// flushed as coalesced 64-float stores (wave0=A, wave1=B).
__global__ __launch_bounds__(256)
__attribute__((amdgpu_waves_per_eu(2, 2)))
void lstm2_kernel(const float* __restrict__ x,
                  const float* __restrict__ W1,
                  const float* __restrict__ b1,
                  const float* __restrict__ W2,
                  const float* __restrict__ b2,
                  float* __restrict__ out)
{
    __shared__ __align__(16) float xA[TT + 4];     // +4: unroll-tail overread
    __shared__ __align__(16) float xB[TT + 4];
    __shared__ __align__(16) float h1A[2][64];     // parity-dbuf h1 broadcast
    __shared__ __align__(16) float h1B[2][64];
    __shared__ __align__(16) float zp[4][2][4];    // [ring][stream][gate]
    __shared__ __align__(16) float h2buf[2][2][64];// [ring][stream][step&63]

    const int tid  = threadIdx.x;
    const int wave = tid >> 6;
    const int lane = tid & 63;
    const int b    = blockIdx.x;

    for (int i = tid; i < TT; i += 256) {
        xA[i] = x[(2 * b) * TT + i];
        xB[i] = x[(2 * b + 1) * TT + i];
    }

    const int g    = lane & 3;          // gate (i,j,f,o)
    const int u    = lane >> 2;         // local unit
    const int unit = (wave << 4) + u;   // global unit 0..63
    const int col  = (g << 6) + unit;   // W1 (65,256) column

#define DECLW(q) \
    const float wx##q = W1[(4*(q)+1)*256 + col]; \
    const float wy##q = W1[(4*(q)+2)*256 + col]; \
    const float wz##q = W1[(4*(q)+3)*256 + col]; \
    const float ww##q = W1[(4*(q)+4)*256 + col];
    DECLW(0)  DECLW(1)  DECLW(2)  DECLW(3)
    DECLW(4)  DECLW(5)  DECLW(6)  DECLW(7)
    DECLW(8)  DECLW(9)  DECLW(10) DECLW(11)
    DECLW(12) DECLW(13) DECLW(14) DECLW(15)
#undef DECLW

    const float w0x   = W1[col];
    const float bias  = b1[col];
    const float w2g   = W2[lane * 4 + wave];     // layer-2 h-part, gate=wave
    const float fbias = (g == 2) ? 1.0f : 0.0f;  // forget-gate bias
    const float nlm   = (g == 1) ? -2.0f : -1.0f;
    const bool  isj   = (g == 1);

    const float w2h0 = W2[256], w2h1 = W2[257], w2h2 = W2[258], w2h3 = W2[259];
    const float b20 = b2[0], b21 = b2[1], b22 = b2[2], b23 = b2[3];

    float c1A = 0.0f, c1B = 0.0f;        // redundant per quad
    float c2 = 0.0f, h2 = 0.0f;          // chain state (wave2 lanes 0/32)

    if (tid < 64) { h1A[0][tid] = 0.0f; h1B[0][tid] = 0.0f; }
    __syncthreads();

#define STEP(P, t, xav, xbv)                                                  \
    {                                                                         \
        if ((t) < TT) {                                                       \
            const float* hA = h1A[P];                                         \
            const float* hB = h1B[P];                                         \
            float a0 = fmaf((xav), w0x, bias), a1 = 0.f, a2 = 0.f, a3 = 0.f;  \
            float d0 = fmaf((xbv), w0x, bias), d1 = 0.f, d2 = 0.f, d3 = 0.f;  \
            FMA8(0)  FMA8(1)  FMA8(2)  FMA8(3)                                \
            FMA8(4)  FMA8(5)  FMA8(6)  FMA8(7)                                \
            FMA8(8)  FMA8(9)  FMA8(10) FMA8(11)                               \
            FMA8(12) FMA8(13) FMA8(14) FMA8(15)                               \
            const float accA = (a0 + a1) + (a2 + a3);                         \
            const float accB = (d0 + d1) + (d2 + d3);                         \
            const float eA = __expf((accA + fbias) * nlm);                    \
            const float eB = __expf((accB + fbias) * nlm);                    \
            const float rA = rcpf(1.0f + eA);                                 \
            const float rB = rcpf(1.0f + eB);                                 \
            const float vA = isj ? fmaf(2.0f, rA, -1.0f) : rA;                \
            const float vB = isj ? fmaf(2.0f, rB, -1.0f) : rB;                \
            const float giA = qbcast<0>(vA), giB = qbcast<0>(vB);             \
            const float gjA = qbcast<1>(vA), gjB = qbcast<1>(vB);             \
            const float gfA = qbcast<2>(vA), gfB = qbcast<2>(vB);             \
            const float goA = qbcast<3>(vA), goB = qbcast<3>(vB);             \
            c1A = fmaf(c1A, gfA, giA * gjA);                                  \
            c1B = fmaf(c1B, gfB, giB * gjB);                                  \
            const float h1vA = ftanh(c1A) * goA;                              \
            const float h1vB = ftanh(c1B) * goB;                              \
            if (g == 0) {                                                     \
                h1A[(P) ^ 1][unit] = h1vA;                                    \
                h1B[(P) ^ 1][unit] = h1vB;                                    \
            }                                                                 \
        }                                                                     \
        if ((t) >= 1 && (t) <= TT) {                                          \
            const float sA = wave_sum63(h1A[P][lane] * w2g);                  \
            const float sB = wave_sum63(h1B[P][lane] * w2g);                  \
            if (lane == 63) {                                                 \
                zp[((t) - 1) & 3][0][wave] = sA;                              \
                zp[((t) - 1) & 3][1][wave] = sB;                              \
            }                                                                 \
        }                                                                     \
        if (wave == 2 && (lane & 31) == 0 && (t) >= 2 && (t) <= TT + 1) {     \
            const int st = (t) - 2;                                           \
            const int s  = lane >> 5;            /* 0=A, 1=B */               \
            const float4 z4 = *(const float4*)zp[st & 3][s];                  \
            const float zi = z4.x + fmaf(h2, w2h0, b20);                      \
            const float zj = z4.y + fmaf(h2, w2h1, b21);                      \
            const float zf = z4.z + fmaf(h2, w2h2, b22);                      \
            const float zo = z4.w + fmaf(h2, w2h3, b23);                      \
            c2 = c2 * fsig(zf + 1.0f) + fsig(zi) * ftanh(zj);                 \
            h2 = ftanh(c2) * fsig(zo);                                        \
            h2buf[(st >> 6) & 1][s][st & 63] = h2;                            \
        }                                                                     \
        __syncthreads();                                                      \
        if ((t) >= 66 && ((t) & 63) == 2 && wave < 2) {                       \
            const int blk = ((t) - 66) >> 6;                                  \
            float* o = out + (2 * b + wave) * TT;                             \
            o[(blk << 6) + lane] = h2buf[blk & 1][wave][lane];                \
        }                                                                     \
    }

#define FMA8(q)                                                               \
    a0 = fmaf(hA[4*(q)+0], wx##q, a0); d0 = fmaf(hB[4*(q)+0], wx##q, d0);     \
    a1 = fmaf(hA[4*(q)+1], wy##q, a1); d1 = fmaf(hB[4*(q)+1], wy##q, d1);     \
    a2 = fmaf(hA[4*(q)+2], wz##q, a2); d2 = fmaf(hB[4*(q)+2], wz##q, d2);     \
    a3 = fmaf(hA[4*(q)+3], ww##q, a3); d3 = fmaf(hB[4*(q)+3], ww##q, d3);

    for (int it = 0; it <= TT + 2; it += 2) {
        const float2 xa = *(const float2*)&xA[it];
        const float2 xb = *(const float2*)&xB[it];
        STEP(0, it,     xa.x, xb.x)
        STEP(1, it + 1, xa.y, xb.y)
    }
#undef FMA8
#undef STEP
}

extern "C" void kernel_launch(void* const* d_in, const int* in_sizes, int n_in,
                              void* d_out, int out_size, void* d_ws, size_t ws_size,
                              hipStream_t stream)
{
    const float* x  = (const float*)d_in[0];
    const float* W1 = (const float*)d_in[1];
    const float* b1 = (const float*)d_in[2];
    const float* W2 = (const float*)d_in[3];
    const float* b2 = (const float*)d_in[4];
    float* out = (float*)d_out;
    lstm2_kernel<<<NB, 256, 0, stream>>>(x, W1, b1, W2, b2, out);
}